// Round 8
// baseline (274.938 us; speedup 1.0000x reference)
//
#include <hip/hip_runtime.h>

#define KDIM 1024

typedef _Float16 half8 __attribute__((ext_vector_type(8)));
typedef _Float16 half4 __attribute__((ext_vector_type(4)));
typedef __fp16 fp16x2 __attribute__((ext_vector_type(2)));
typedef __fp16 fp16x4 __attribute__((ext_vector_type(4)));
typedef float f32x4 __attribute__((ext_vector_type(4)));

#if defined(__has_builtin)
#if __has_builtin(__builtin_amdgcn_global_load_lds)
#define HAVE_GLDS 1
#endif
#if __has_builtin(__builtin_amdgcn_exp2f)
#define EXP2(x) __builtin_amdgcn_exp2f(x)
#endif
#if __has_builtin(__builtin_amdgcn_cvt_pkrtz)
#define HAVE_PKRTZ 1
#endif
#if __has_builtin(__builtin_amdgcn_fdot2)
#define HAVE_FDOT2 1
#endif
#endif
#ifndef EXP2
#define EXP2(x) exp2f(x)
#endif

__device__ __forceinline__ void stage16(const _Float16* g, _Float16* wave_base, int lane) {
#ifdef HAVE_GLDS
  __builtin_amdgcn_global_load_lds(
      (const __attribute__((address_space(1))) void*)g,
      (__attribute__((address_space(3))) void*)wave_base, 16, 0, 0);
#else
  *(half8*)(wave_base + lane * 8) = *(const half8*)g;
#endif
}

#define BARRIER() __builtin_amdgcn_s_barrier()

// ------------- merged prep: cast x | transpose-cast W | mask bits -------------
__global__ void prep_kernel(const float* __restrict__ x, const float* __restrict__ am,
                            const float* __restrict__ Wq, const float* __restrict__ Wk,
                            const float* __restrict__ Wv, _Float16* __restrict__ xb,
                            _Float16* __restrict__ Wqkvt, unsigned long long* __restrict__ bits) {
  __shared__ _Float16 tile[32][33];
  int bid = blockIdx.x;
  if (bid < 8192) {
    size_t i = ((size_t)bid * 256 + threadIdx.x) * 4;
    float4 v = *(const float4*)(x + i);
    half4 h = { (_Float16)v.x, (_Float16)v.y, (_Float16)v.z, (_Float16)v.w };
    *(half4*)(xb + i) = h;
  } else if (bid < 11264) {
    int zz = bid - 8192;
    int z = zz >> 10;
    int rem = zz & 1023;
    int bx = rem & 31, by = rem >> 5;
    const float* src = z == 0 ? Wq : (z == 1 ? Wk : Wv);
    _Float16* dst = Wqkvt + (size_t)z * KDIM * KDIM;
    float sc = (z == 0) ? 0.18033688011112042f : 1.0f;  // (1/8)*log2(e)
    int tx = threadIdx.x & 31, ty = threadIdx.x >> 5;
    int c0 = bx * 32, r0 = by * 32;
#pragma unroll
    for (int i = 0; i < 4; i++) {
      int r = r0 + ty + i * 8;
      tile[tx][ty + i * 8] = (_Float16)(src[(size_t)r * KDIM + c0 + tx] * sc);
    }
    __syncthreads();
#pragma unroll
    for (int i = 0; i < 4; i++) {
      int n = c0 + ty + i * 8;
      dst[(size_t)n * KDIM + r0 + tx] = tile[ty + i * 8][tx];
    }
  } else {
    size_t i = (size_t)(bid - 11264) * 256 + threadIdx.x;
    unsigned long long b = __ballot(am[i] != 0.0f);
    if ((threadIdx.x & 63) == 0) bits[i >> 6] = b;
  }
}

// ---------------- fused QKV GEMM, 256x192 tile, BK=32, 2 blocks/CU, 1 barrier/tile ----------
// (byte-identical to R7 — main loop measured at the m97-structure ceiling)
__global__ __launch_bounds__(512, 4)
void gemm_kernel(const _Float16* __restrict__ A, const _Float16* __restrict__ Bt,
                 _Float16* __restrict__ Qt, _Float16* __restrict__ Kh,
                 _Float16* __restrict__ Vth) {
  __shared__ _Float16 As[2 * 8192];   // [buf][256 rows][32]
  __shared__ _Float16 Bs[2 * 6144];   // [buf][192 rows][32]
  int tid = threadIdx.x;
  int lane = tid & 63, w = tid >> 6;
  int la = lane & 15, qd = lane >> 4;
  int wm = w & 1, wn = w >> 1;  // 2M x 4N waves; per-wave out 128 x 48 (3 n-frags strided 64)
  // XCD swizzle: 512 blocks, 64 consecutive wgs per XCD (512 % 8 == 0 -> bijective)
  int bid = blockIdx.x;
  int wg = (bid & 7) * 64 + (bid >> 3);
  int by = wg >> 4, bx = wg & 15;
  int m0 = by * 256, n0 = bx * 192;

  // staging: slice = 16 rows x 32 halves = 1KB/wave. lane ln: row ln>>2, phys chunk ln&3,
  // logical source chunk (ln&3) ^ ((ln>>3)&3)
  int srow = lane >> 2;
  int slc = ((lane & 3) ^ ((lane >> 3) & 3)) << 3;  // source chunk offset in halves
  const _Float16* Ab = A + (size_t)m0 * KDIM;
  const _Float16* Bb = Bt + (size_t)n0 * KDIM;
  const _Float16* pAa = Ab + (size_t)(w * 16 + srow) * KDIM + slc;
  const _Float16* pAb = Ab + (size_t)(128 + w * 16 + srow) * KDIM + slc;
  const _Float16* pBa = Bb + (size_t)(w * 16 + srow) * KDIM + slc;
  const _Float16* pBb = Bb + (size_t)(128 + w * 16 + srow) * KDIM + slc;  // waves 0-3 only

  _Float16* ldsA0 = As + w * 512;         // rows w*16..w*16+15
  _Float16* ldsA1 = As + 4096 + w * 512;  // rows 128+w*16..
  _Float16* ldsB0 = Bs + w * 512;
  _Float16* ldsB1 = Bs + 4096 + w * 512;  // rows 128..191 (waves 0-3)

  // read-side: logical chunk qd at phys chunk qd ^ ((la>>1)&3)
  const int rc = ((qd ^ ((la >> 1) & 3)) << 3);
  const _Float16* baseA = As + (wm * 64 + la) * 32 + rc;
  const _Float16* baseB = Bs + (wn * 16 + la) * 32 + rc;

  f32x4 acc[8][3] = {};
  half8 bf[3];

#define STAGE_AB(B)                                            \
  do {                                                         \
    stage16(pAa, ldsA0 + (B) * 8192, lane);                    \
    stage16(pAb, ldsA1 + (B) * 8192, lane);                    \
    stage16(pBa, ldsB0 + (B) * 6144, lane);                    \
    if (w < 4) stage16(pBb, ldsB1 + (B) * 6144, lane);         \
    pAa += 32; pAb += 32; pBa += 32; pBb += 32;                \
  } while (0)

// A-frag a = mh*4+mi lives at rows mh*128 + mi*16 (+wm*64+la): offset mh*4096 + mi*512 halves.
#define TILE(T, CUR, NXT)                                                       \
  do {                                                                          \
    if ((T) < 31) STAGE_AB(NXT);                                                \
    _Pragma("unroll") for (int nj = 0; nj < 3; ++nj)                            \
        bf[nj] = *(const half8*)(baseB + (CUR) * 6144 + nj * 2048);             \
    __builtin_amdgcn_s_setprio(1);                                              \
    _Pragma("unroll") for (int a = 0; a < 8; ++a) {                             \
      half8 afa = *(const half8*)(baseA + (CUR) * 8192 + (a >> 2) * 4096 +      \
                                  (a & 3) * 512);                               \
      _Pragma("unroll") for (int nj = 0; nj < 3; ++nj)                          \
          acc[a][nj] = __builtin_amdgcn_mfma_f32_16x16x32_f16(                  \
              afa, bf[nj], acc[a][nj], 0, 0, 0);                                \
    }                                                                           \
    __builtin_amdgcn_s_setprio(0);                                              \
    __syncthreads();                                                            \
  } while (0)

  // Prologue: stage tile 0 into buf 0, full drain barrier.
  STAGE_AB(0);
  __syncthreads();

#pragma unroll 1
  for (int tp = 0; tp < 16; ++tp) {
    TILE(2 * tp, 0, 1);
    TILE(2 * tp + 1, 1, 0);
  }

#undef TILE
#undef STAGE_AB

  // ---------------- epilogue (per-frag Q/K/V routing; acc[mh*4+mi][nj]) ----------
  int rr = lane >> 2, c4 = lane & 3;
  _Float16* ep = As + w * 1280;  // wave-private 16x72 transpose patch
#pragma unroll
  for (int mh = 0; mh < 2; ++mh) {
    int srow0 = m0 + mh * 128 + wm * 64;
    int b = srow0 >> 10, s0 = srow0 & 1023;
#pragma unroll
    for (int nj = 0; nj < 3; ++nj) {
      int colh = n0 + wn * 16 + nj * 64;
      int whichf = colh >> 10;       // 0:Q 1:K 2:V (uniform per wave,nj)
      int cm = colh & 1023;
      int hh = cm >> 6, d0 = cm & 63;
      if (whichf == 1) {
        _Float16* kb = Kh + (size_t)(b * 16 + hh) * 1024 * 64;
#pragma unroll
        for (int mi = 0; mi < 4; ++mi) {
          f32x4 v = acc[mh * 4 + mi][nj];
          int s = s0 + mi * 16 + qd * 4;
#pragma unroll
          for (int rg = 0; rg < 4; ++rg)
            kb[(size_t)(s + rg) * 64 + d0 + la] = (_Float16)v[rg];
        }
      } else {
        _Float16* dst = (whichf == 0) ? Qt : Vth;
#pragma unroll
        for (int mi = 0; mi < 4; ++mi) {
          f32x4 v = acc[mh * 4 + mi][nj];
          half4 hv = { (_Float16)v[0], (_Float16)v[1], (_Float16)v[2], (_Float16)v[3] };
          *(half4*)(ep + la * 72 + mi * 16 + qd * 4) = hv;  // row=d(la), col=s
        }
        half8 o0 = *(const half8*)(ep + rr * 72 + c4 * 16);
        half8 o1 = *(const half8*)(ep + rr * 72 + c4 * 16 + 8);
        _Float16* gp = dst + ((size_t)(b * 16 + hh) * 64 + d0 + rr) * 1024 + s0 + c4 * 16;
        *(half8*)gp = o0;
        *(half8*)(gp + 8) = o1;
      }
    }
  }
}

// ---------------- fused attention: 2-tile super-iters (8 barriers) + LUT pk_mul mask ----------
__global__ __launch_bounds__(512, 2)
void attn_kernel(const _Float16* __restrict__ Qt, const _Float16* __restrict__ K,
                 const _Float16* __restrict__ Vt, const unsigned long long* __restrict__ mbits,
                 float* __restrict__ out) {
  __shared__ _Float16 Ks[4][2 * 64 * 32];  // 4 buffers (8KB each)
  __shared__ _Float16 Vs[4][2 * 64 * 40];  // 4 buffers (10KB each, padded)
  __shared__ _Float16 lut16[16][4];        // nibble -> {0,1} half4
  int tid = threadIdx.x;
  int lane = tid & 63, w4 = tid >> 6;  // w4 0..7
  int la = lane & 15, qd = lane >> 4;
  if (tid < 64) lut16[tid >> 2][tid & 3] = (_Float16)(float)(((tid >> 2) >> (tid & 3)) & 1);
  int linear = blockIdx.x;
  int xlo = linear & 7;
  int tmp = linear >> 3;  // 0..63
  int qt = tmp & 3;
  int hb = (tmp >> 2) * 8 + xlo;  // 0..127
  int h = hb & 15, b = hb >> 4;
  const _Float16* Qp = Qt + (size_t)hb * 64 * 1024;  // [d][s]
  const _Float16* Kp = K + (size_t)hb * 1024 * 64;   // [s][d]
  const _Float16* Vp = Vt + (size_t)hb * 64 * 1024;  // [d][s]
  int q0w = qt * 256 + w4 * 16;  // qfrag qi adds qi*128
  half8 qf[2][2];
#pragma unroll
  for (int qi = 0; qi < 2; qi++)
#pragma unroll
    for (int ks = 0; ks < 2; ks++)
#pragma unroll
      for (int j = 0; j < 8; j++)
        qf[qi][ks][j] = Qp[(size_t)(ks * 32 + qd * 8 + j) * 1024 + q0w + qi * 128 + la];
  unsigned long long mq[2][4];
#pragma unroll
  for (int qi = 0; qi < 2; qi++) {
    const ulonglong2* mp =
        (const ulonglong2*)(mbits + ((size_t)b * 1024 + q0w + qi * 128 + la) * 16 + qd * 4);
    ulonglong2 m01 = mp[0];
    ulonglong2 m23 = mp[1];
    mq[qi][0] = m01.x; mq[qi][1] = m01.y; mq[qi][2] = m23.x; mq[qi][3] = m23.y;
  }
  f32x4 acco[2][4] = {};
  float rs[2] = {0.f, 0.f};
  int kt_t = (tid & 255) >> 2;
  int kt_d = (tid >> 8) * 32 + (((tid & 3) ^ ((tid >> 2) & 3) ^ ((tid >> 4) & 3)) << 3);
  int kc8 = ((qd ^ (la & 3) ^ (la >> 2)) << 3);
  int vd = tid >> 3;
  int vt = (tid & 7) * 8;
  int vs_off = (vt >= 32 ? 2560 : 0) + vd * 40 + (vt & 31);
#if defined(HAVE_FDOT2) && defined(HAVE_PKRTZ)
  fp16x2 one2 = { (__fp16)1.0f, (__fp16)1.0f };
#endif
  // prologue: V(0),V(1) to regs; stage K(0),K(1); write Vs; full drain; barrier.
  {
    half8 vv0 = *(const half8*)(Vp + (size_t)vd * 1024 + vt);
    half8 vv1 = *(const half8*)(Vp + (size_t)vd * 1024 + 64 + vt);
    __builtin_amdgcn_sched_barrier(0);
    stage16(Kp + (size_t)kt_t * 64 + kt_d, Ks[0] + w4 * 512, lane);
    stage16(Kp + (size_t)(64 + kt_t) * 64 + kt_d, Ks[1] + w4 * 512, lane);
    *(half8*)(Vs[0] + vs_off) = vv0;
    *(half8*)(Vs[1] + vs_off) = vv1;
  }
  asm volatile("s_waitcnt vmcnt(0) lgkmcnt(0)" ::: "memory");
  BARRIER();

  // one tile of QK^T + masked-exp + PV (tt folded to constants by unroll)
  auto compute_tile = [&](int tt) {
    const _Float16* ks_ = Ks[tt & 3];
    const _Float16* vs_ = Vs[tt & 3];
    unsigned long long mw0 = __shfl(mq[0][tt & 3], ((tt >> 2) << 4) + la);
    unsigned long long mw1 = __shfl(mq[1][tt & 3], ((tt >> 2) << 4) + la);
    unsigned long long mq0s = mw0 >> (qd * 4);
    unsigned long long mq1s = mw1 >> (qd * 4);
#pragma unroll
    for (int tsub = 0; tsub < 4; tsub++) {
      half8 kf0 = *(const half8*)(ks_ + (tsub * 16 + la) * 32 + kc8);
      half8 kf1 = *(const half8*)(ks_ + 2048 + (tsub * 16 + la) * 32 + kc8);
      f32x4 a0 = {}, a1 = {};
      __builtin_amdgcn_s_setprio(1);
      a0 = __builtin_amdgcn_mfma_f32_16x16x32_f16(kf0, qf[0][0], a0, 0, 0, 0);
      a1 = __builtin_amdgcn_mfma_f32_16x16x32_f16(kf0, qf[1][0], a1, 0, 0, 0);
      a0 = __builtin_amdgcn_mfma_f32_16x16x32_f16(kf1, qf[0][1], a0, 0, 0, 0);
      a1 = __builtin_amdgcn_mfma_f32_16x16x32_f16(kf1, qf[1][1], a1, 0, 0, 0);
      __builtin_amdgcn_s_setprio(0);
      half4 pf[2];
#pragma unroll
      for (int qi = 0; qi < 2; qi++) {
        const f32x4& aa = qi ? a1 : a0;
        unsigned nib = (unsigned)((qi ? mq1s : mq0s) >> (tsub * 16)) & 15u;
#ifdef HAVE_PKRTZ
        // unconditional exp (bounded: |scores*log2e/8| <~ 9 -> e <= 2^9 << f16 max),
        // mask applied as exact packed multiply by {0,1} LUT halves.
        float e0 = EXP2(aa[0]);
        float e1 = EXP2(aa[1]);
        float e2 = EXP2(aa[2]);
        float e3 = EXP2(aa[3]);
        fp16x4 lv = *(const fp16x4*)lut16[nib];  // ds_read_b64, conflict-free
        fp16x2 l01 = __builtin_shufflevector(lv, lv, 0, 1);
        fp16x2 l23 = __builtin_shufflevector(lv, lv, 2, 3);
        fp16x2 p01 = __builtin_amdgcn_cvt_pkrtz(e0, e1) * l01;  // v_pk_mul_f16
        fp16x2 p23 = __builtin_amdgcn_cvt_pkrtz(e2, e3) * l23;
        fp16x4 pfv = __builtin_shufflevector(p01, p23, 0, 1, 2, 3);
        pf[qi] = __builtin_bit_cast(half4, pfv);
#if defined(HAVE_FDOT2)
        rs[qi] = __builtin_amdgcn_fdot2(p01, one2, rs[qi], false);
        rs[qi] = __builtin_amdgcn_fdot2(p23, one2, rs[qi], false);
#else
        rs[qi] += (float)p01[0] + (float)p01[1] + (float)p23[0] + (float)p23[1];
#endif
#else
        float e0 = (nib & 1u) ? EXP2(aa[0]) : 0.0f;
        float e1 = (nib & 2u) ? EXP2(aa[1]) : 0.0f;
        float e2 = (nib & 4u) ? EXP2(aa[2]) : 0.0f;
        float e3 = (nib & 8u) ? EXP2(aa[3]) : 0.0f;
        pf[qi][0] = (_Float16)e0; pf[qi][1] = (_Float16)e1;
        pf[qi][2] = (_Float16)e2; pf[qi][3] = (_Float16)e3;
        rs[qi] += e0 + e1 + e2 + e3;
#endif
      }
#pragma unroll
      for (int nsub = 0; nsub < 4; nsub++) {
        half4 vf = *(const half4*)(vs_ + (tsub >> 1) * 2560 + (nsub * 16 + la) * 40 +
                                   (tsub & 1) * 16 + qd * 4);
        __builtin_amdgcn_s_setprio(1);
        acco[0][nsub] = __builtin_amdgcn_mfma_f32_16x16x16f16(pf[0], vf, acco[0][nsub], 0, 0, 0);
        acco[1][nsub] = __builtin_amdgcn_mfma_f32_16x16x16f16(pf[1], vf, acco[1][nsub], 0, 0, 0);
        __builtin_amdgcn_s_setprio(0);
      }
    }
  };

#pragma unroll
  for (int u = 0; u < 8; ++u) {
    half8 vvA, vvB;
    if (u < 7) {
      vvA = *(const half8*)(Vp + (size_t)vd * 1024 + (2 * u + 2) * 64 + vt);
      vvB = *(const half8*)(Vp + (size_t)vd * 1024 + (2 * u + 3) * 64 + vt);
      __builtin_amdgcn_sched_barrier(0);
      stage16(Kp + (size_t)((2 * u + 2) * 64 + kt_t) * 64 + kt_d,
              Ks[(2 * u + 2) & 3] + w4 * 512, lane);
      stage16(Kp + (size_t)((2 * u + 3) * 64 + kt_t) * 64 + kt_d,
              Ks[(2 * u + 3) & 3] + w4 * 512, lane);
    }
    compute_tile(2 * u);
    if (u < 7) *(half8*)(Vs[(2 * u + 2) & 3] + vs_off) = vvA;  // implicit wait keeps K stages in flight
    compute_tile(2 * u + 1);
    if (u < 7) {
      *(half8*)(Vs[(2 * u + 3) & 3] + vs_off) = vvB;
      // K(2u+2),K(2u+3) have had two full tiles of compute to land; drain + handshake.
      asm volatile("s_waitcnt vmcnt(0) lgkmcnt(0)" ::: "memory");
      BARRIER();
    }
  }

  float* op = out + (size_t)b * 1024 * 1024 + (size_t)h * 64;
#pragma unroll
  for (int qi = 0; qi < 2; qi++) {
    float r0 = rs[qi];
    r0 += __shfl_xor(r0, 16);
    r0 += __shfl_xor(r0, 32);
    float inv_q = 1.0f / (r0 + 1e-8f);
#pragma unroll
    for (int rg = 0; rg < 4; rg++) {
      float inv = __shfl(inv_q, qd * 4 + rg);
      int s = q0w + qi * 128 + qd * 4 + rg;
#pragma unroll
      for (int nsub = 0; nsub < 4; nsub++)
        op[(size_t)s * 1024 + nsub * 16 + la] = acco[qi][nsub][rg] * inv;
    }
  }
}

extern "C" void kernel_launch(void* const* d_in, const int* in_sizes, int n_in,
                              void* d_out, int out_size, void* d_ws, size_t ws_size,
                              hipStream_t stream) {
  (void)in_sizes; (void)n_in; (void)out_size; (void)ws_size;
  const float* x = (const float*)d_in[0];
  const float* am = (const float*)d_in[1];
  const float* Wq = (const float*)d_in[2];
  const float* Wk = (const float*)d_in[3];
  const float* Wv = (const float*)d_in[4];
  float* out = (float*)d_out;

  char* p = (char*)d_ws;
  _Float16* xb = (_Float16*)p;    p += (size_t)8192 * 1024 * 2;
  _Float16* Wqkvt = (_Float16*)p; p += (size_t)3 * 1024 * 1024 * 2;
  _Float16* Qt = (_Float16*)p;    p += (size_t)8192 * 1024 * 2;   // [b,h,d,s]
  _Float16* Kh = (_Float16*)p;    p += (size_t)8192 * 1024 * 2;   // [b,h,s,d]
  _Float16* Vth = (_Float16*)p;   p += (size_t)8192 * 1024 * 2;   // [b,h,d,s]
  unsigned long long* mb = (unsigned long long*)p;

  prep_kernel<<<44032, 256, 0, stream>>>(x, am, Wq, Wk, Wv, xb, Wqkvt, mb);
  gemm_kernel<<<dim3(512), 512, 0, stream>>>(xb, Wqkvt, Qt, Kh, Vth);
  attn_kernel<<<512, 512, 0, stream>>>(Qt, Kh, Vth, mb, out);
}

// Round 9
// 225.496 us; speedup vs baseline: 1.2193x; 1.2193x over previous
//
#include <hip/hip_runtime.h>

#define KDIM 1024

typedef _Float16 half8 __attribute__((ext_vector_type(8)));
typedef _Float16 half4 __attribute__((ext_vector_type(4)));
typedef __fp16 fp16x2 __attribute__((ext_vector_type(2)));
typedef __fp16 fp16x4 __attribute__((ext_vector_type(4)));
typedef float f32x4 __attribute__((ext_vector_type(4)));

#if defined(__has_builtin)
#if __has_builtin(__builtin_amdgcn_global_load_lds)
#define HAVE_GLDS 1
#endif
#if __has_builtin(__builtin_amdgcn_exp2f)
#define EXP2(x) __builtin_amdgcn_exp2f(x)
#endif
#if __has_builtin(__builtin_amdgcn_cvt_pkrtz)
#define HAVE_PKRTZ 1
#endif
#if __has_builtin(__builtin_amdgcn_fdot2)
#define HAVE_FDOT2 1
#endif
#endif
#ifndef EXP2
#define EXP2(x) exp2f(x)
#endif

__device__ __forceinline__ void stage16(const _Float16* g, _Float16* wave_base, int lane) {
#ifdef HAVE_GLDS
  __builtin_amdgcn_global_load_lds(
      (const __attribute__((address_space(1))) void*)g,
      (__attribute__((address_space(3))) void*)wave_base, 16, 0, 0);
#else
  *(half8*)(wave_base + lane * 8) = *(const half8*)g;
#endif
}

#define BARRIER() __builtin_amdgcn_s_barrier()

// ------------- merged prep: cast x | transpose-cast W | mask bits (vectorized) -------------
// blocks [0,8192): cast x f32->f16 (float4/lane)
// blocks [8192,11264): W transpose-cast (Wq pre-scaled by (1/8)*log2e)
// blocks [11264,19456): mask bits, float4/lane + shfl-or nibble assembly
__global__ void prep_kernel(const float* __restrict__ x, const float* __restrict__ am,
                            const float* __restrict__ Wq, const float* __restrict__ Wk,
                            const float* __restrict__ Wv, _Float16* __restrict__ xb,
                            _Float16* __restrict__ Wqkvt, unsigned long long* __restrict__ bits) {
  __shared__ _Float16 tile[32][33];
  int bid = blockIdx.x;
  if (bid < 8192) {
    size_t i = ((size_t)bid * 256 + threadIdx.x) * 4;
    float4 v = *(const float4*)(x + i);
    half4 h = { (_Float16)v.x, (_Float16)v.y, (_Float16)v.z, (_Float16)v.w };
    *(half4*)(xb + i) = h;
  } else if (bid < 11264) {
    int zz = bid - 8192;
    int z = zz >> 10;
    int rem = zz & 1023;
    int bx = rem & 31, by = rem >> 5;
    const float* src = z == 0 ? Wq : (z == 1 ? Wk : Wv);
    _Float16* dst = Wqkvt + (size_t)z * KDIM * KDIM;
    float sc = (z == 0) ? 0.18033688011112042f : 1.0f;  // (1/8)*log2(e)
    int tx = threadIdx.x & 31, ty = threadIdx.x >> 5;
    int c0 = bx * 32, r0 = by * 32;
#pragma unroll
    for (int i = 0; i < 4; i++) {
      int r = r0 + ty + i * 8;
      tile[tx][ty + i * 8] = (_Float16)(src[(size_t)r * KDIM + c0 + tx] * sc);
    }
    __syncthreads();
#pragma unroll
    for (int i = 0; i < 4; i++) {
      int n = c0 + ty + i * 8;
      dst[(size_t)n * KDIM + r0 + tx] = tile[ty + i * 8][tx];
    }
  } else {
    // 1024 elements/block: lane reads float4; 16-lane group assembles one u64.
    size_t i4 = ((size_t)(bid - 11264) * 256 + threadIdx.x) * 4;
    float4 v = *(const float4*)(am + i4);
    unsigned nib = (unsigned)(v.x != 0.0f) | ((unsigned)(v.y != 0.0f) << 1) |
                   ((unsigned)(v.z != 0.0f) << 2) | ((unsigned)(v.w != 0.0f) << 3);
    unsigned long long word = (unsigned long long)nib << ((threadIdx.x & 15) * 4);
    word |= __shfl_xor(word, 1);
    word |= __shfl_xor(word, 2);
    word |= __shfl_xor(word, 4);
    word |= __shfl_xor(word, 8);
    if ((threadIdx.x & 15) == 0) bits[i4 >> 6] = word;
  }
}

// ---------------- fused QKV GEMM, 256x192 tile, BK=32, 2 blocks/CU, 1 barrier/tile ----------
// (byte-identical to R7 — main loop measured at the m97-structure ceiling)
__global__ __launch_bounds__(512, 4)
void gemm_kernel(const _Float16* __restrict__ A, const _Float16* __restrict__ Bt,
                 _Float16* __restrict__ Qt, _Float16* __restrict__ Kh,
                 _Float16* __restrict__ Vth) {
  __shared__ _Float16 As[2 * 8192];   // [buf][256 rows][32]
  __shared__ _Float16 Bs[2 * 6144];   // [buf][192 rows][32]
  int tid = threadIdx.x;
  int lane = tid & 63, w = tid >> 6;
  int la = lane & 15, qd = lane >> 4;
  int wm = w & 1, wn = w >> 1;  // 2M x 4N waves; per-wave out 128 x 48 (3 n-frags strided 64)
  // XCD swizzle: 512 blocks, 64 consecutive wgs per XCD (512 % 8 == 0 -> bijective)
  int bid = blockIdx.x;
  int wg = (bid & 7) * 64 + (bid >> 3);
  int by = wg >> 4, bx = wg & 15;
  int m0 = by * 256, n0 = bx * 192;

  // staging: slice = 16 rows x 32 halves = 1KB/wave. lane ln: row ln>>2, phys chunk ln&3,
  // logical source chunk (ln&3) ^ ((ln>>3)&3)
  int srow = lane >> 2;
  int slc = ((lane & 3) ^ ((lane >> 3) & 3)) << 3;  // source chunk offset in halves
  const _Float16* Ab = A + (size_t)m0 * KDIM;
  const _Float16* Bb = Bt + (size_t)n0 * KDIM;
  const _Float16* pAa = Ab + (size_t)(w * 16 + srow) * KDIM + slc;
  const _Float16* pAb = Ab + (size_t)(128 + w * 16 + srow) * KDIM + slc;
  const _Float16* pBa = Bb + (size_t)(w * 16 + srow) * KDIM + slc;
  const _Float16* pBb = Bb + (size_t)(128 + w * 16 + srow) * KDIM + slc;  // waves 0-3 only

  _Float16* ldsA0 = As + w * 512;         // rows w*16..w*16+15
  _Float16* ldsA1 = As + 4096 + w * 512;  // rows 128+w*16..
  _Float16* ldsB0 = Bs + w * 512;
  _Float16* ldsB1 = Bs + 4096 + w * 512;  // rows 128..191 (waves 0-3)

  // read-side: logical chunk qd at phys chunk qd ^ ((la>>1)&3)
  const int rc = ((qd ^ ((la >> 1) & 3)) << 3);
  const _Float16* baseA = As + (wm * 64 + la) * 32 + rc;
  const _Float16* baseB = Bs + (wn * 16 + la) * 32 + rc;

  f32x4 acc[8][3] = {};
  half8 bf[3];

#define STAGE_AB(B)                                            \
  do {                                                         \
    stage16(pAa, ldsA0 + (B) * 8192, lane);                    \
    stage16(pAb, ldsA1 + (B) * 8192, lane);                    \
    stage16(pBa, ldsB0 + (B) * 6144, lane);                    \
    if (w < 4) stage16(pBb, ldsB1 + (B) * 6144, lane);         \
    pAa += 32; pAb += 32; pBa += 32; pBb += 32;                \
  } while (0)

// A-frag a = mh*4+mi lives at rows mh*128 + mi*16 (+wm*64+la): offset mh*4096 + mi*512 halves.
#define TILE(T, CUR, NXT)                                                       \
  do {                                                                          \
    if ((T) < 31) STAGE_AB(NXT);                                                \
    _Pragma("unroll") for (int nj = 0; nj < 3; ++nj)                            \
        bf[nj] = *(const half8*)(baseB + (CUR) * 6144 + nj * 2048);             \
    __builtin_amdgcn_s_setprio(1);                                              \
    _Pragma("unroll") for (int a = 0; a < 8; ++a) {                             \
      half8 afa = *(const half8*)(baseA + (CUR) * 8192 + (a >> 2) * 4096 +      \
                                  (a & 3) * 512);                               \
      _Pragma("unroll") for (int nj = 0; nj < 3; ++nj)                          \
          acc[a][nj] = __builtin_amdgcn_mfma_f32_16x16x32_f16(                  \
              afa, bf[nj], acc[a][nj], 0, 0, 0);                                \
    }                                                                           \
    __builtin_amdgcn_s_setprio(0);                                              \
    __syncthreads();                                                            \
  } while (0)

  // Prologue: stage tile 0 into buf 0, full drain barrier.
  STAGE_AB(0);
  __syncthreads();

#pragma unroll 1
  for (int tp = 0; tp < 16; ++tp) {
    TILE(2 * tp, 0, 1);
    TILE(2 * tp + 1, 1, 0);
  }

#undef TILE
#undef STAGE_AB

  // ---------------- epilogue (per-frag Q/K/V routing; acc[mh*4+mi][nj]) ----------
  int rr = lane >> 2, c4 = lane & 3;
  _Float16* ep = As + w * 1280;  // wave-private 16x72 transpose patch
#pragma unroll
  for (int mh = 0; mh < 2; ++mh) {
    int srow0 = m0 + mh * 128 + wm * 64;
    int b = srow0 >> 10, s0 = srow0 & 1023;
#pragma unroll
    for (int nj = 0; nj < 3; ++nj) {
      int colh = n0 + wn * 16 + nj * 64;
      int whichf = colh >> 10;       // 0:Q 1:K 2:V (uniform per wave,nj)
      int cm = colh & 1023;
      int hh = cm >> 6, d0 = cm & 63;
      if (whichf == 1) {
        _Float16* kb = Kh + (size_t)(b * 16 + hh) * 1024 * 64;
#pragma unroll
        for (int mi = 0; mi < 4; ++mi) {
          f32x4 v = acc[mh * 4 + mi][nj];
          int s = s0 + mi * 16 + qd * 4;
#pragma unroll
          for (int rg = 0; rg < 4; ++rg)
            kb[(size_t)(s + rg) * 64 + d0 + la] = (_Float16)v[rg];
        }
      } else {
        _Float16* dst = (whichf == 0) ? Qt : Vth;
#pragma unroll
        for (int mi = 0; mi < 4; ++mi) {
          f32x4 v = acc[mh * 4 + mi][nj];
          half4 hv = { (_Float16)v[0], (_Float16)v[1], (_Float16)v[2], (_Float16)v[3] };
          *(half4*)(ep + la * 72 + mi * 16 + qd * 4) = hv;  // row=d(la), col=s
        }
        half8 o0 = *(const half8*)(ep + rr * 72 + c4 * 16);
        half8 o1 = *(const half8*)(ep + rr * 72 + c4 * 16 + 8);
        _Float16* gp = dst + ((size_t)(b * 16 + hh) * 64 + d0 + rr) * 1024 + s0 + c4 * 16;
        *(half8*)gp = o0;
        *(half8*)(gp + 8) = o1;
      }
    }
  }
}

// ---------------- fused attention: R4 structure (verified 67.0us) + LUT pk_mul mask ----------
__global__ __launch_bounds__(512, 2)
void attn_kernel(const _Float16* __restrict__ Qt, const _Float16* __restrict__ K,
                 const _Float16* __restrict__ Vt, const unsigned long long* __restrict__ mbits,
                 float* __restrict__ out) {
  __shared__ _Float16 Ks[4][2 * 64 * 32];  // 4 buffers, 2-ahead pipeline (8KB each)
  __shared__ _Float16 Vs[2][2 * 64 * 40];  // [buf][tc=t/32][d][40 padded]
  __shared__ __align__(8) _Float16 lut16[16][4];  // nibble -> {0,1} half4
  int tid = threadIdx.x;
  int lane = tid & 63, w4 = tid >> 6;  // w4 0..7
  int la = lane & 15, qd = lane >> 4;
  if (tid < 64) lut16[tid >> 2][tid & 3] = (_Float16)(float)(((tid >> 2) >> (tid & 3)) & 1);
  int linear = blockIdx.x;
  int xlo = linear & 7;
  int tmp = linear >> 3;  // 0..63
  int qt = tmp & 3;
  int hb = (tmp >> 2) * 8 + xlo;  // 0..127
  int h = hb & 15, b = hb >> 4;
  const _Float16* Qp = Qt + (size_t)hb * 64 * 1024;  // [d][s]
  const _Float16* Kp = K + (size_t)hb * 1024 * 64;   // [s][d]
  const _Float16* Vp = Vt + (size_t)hb * 64 * 1024;  // [d][s]
  int q0w = qt * 256 + w4 * 16;  // qfrag qi adds qi*128
  half8 qf[2][2];
#pragma unroll
  for (int qi = 0; qi < 2; qi++)
#pragma unroll
    for (int ks = 0; ks < 2; ks++)
#pragma unroll
      for (int j = 0; j < 8; j++)
        qf[qi][ks][j] = Qp[(size_t)(ks * 32 + qd * 8 + j) * 1024 + q0w + qi * 128 + la];
  unsigned long long mq[2][4];
#pragma unroll
  for (int qi = 0; qi < 2; qi++) {
    const ulonglong2* mp =
        (const ulonglong2*)(mbits + ((size_t)b * 1024 + q0w + qi * 128 + la) * 16 + qd * 4);
    ulonglong2 m01 = mp[0];
    ulonglong2 m23 = mp[1];
    mq[qi][0] = m01.x; mq[qi][1] = m01.y; mq[qi][2] = m23.x; mq[qi][3] = m23.y;
  }
  f32x4 acco[2][4] = {};
  float rs[2] = {0.f, 0.f};
  int kt_t = (tid & 255) >> 2;
  int kt_d = (tid >> 8) * 32 + (((tid & 3) ^ ((tid >> 2) & 3) ^ ((tid >> 4) & 3)) << 3);
  int kc8 = ((qd ^ (la & 3) ^ (la >> 2)) << 3);
  int vd = tid >> 3;
  int vt = (tid & 7) * 8;
  int vs_off = (vt >= 32 ? 2560 : 0) + vd * 40 + (vt & 31);
#if defined(HAVE_FDOT2) && defined(HAVE_PKRTZ)
  fp16x2 one2 = { (__fp16)1.0f, (__fp16)1.0f };
#endif
  // prologue: issue V(0) first (oldest), then K(0), K(1); leave K(1) in flight.
  {
    half8 vv0 = *(const half8*)(Vp + (size_t)vd * 1024 + vt);
    __builtin_amdgcn_sched_barrier(0);
    stage16(Kp + (size_t)kt_t * 64 + kt_d, Ks[0] + w4 * 512, lane);
    stage16(Kp + (size_t)(64 + kt_t) * 64 + kt_d, Ks[1] + w4 * 512, lane);
    *(half8*)(Vs[0] + vs_off) = vv0;  // implicit wait retires vv0 (and nothing newer)
  }
  asm volatile("s_waitcnt vmcnt(1) lgkmcnt(0)" ::: "memory");
  BARRIER();
  for (int tt = 0; tt < 16; tt++) {
    const _Float16* ks_ = Ks[tt & 3];
    const _Float16* vs_ = Vs[tt & 1];
    half8 vvn;
    if (tt < 15) {
      vvn = *(const half8*)(Vp + (size_t)vd * 1024 + (tt + 1) * 64 + vt);
      __builtin_amdgcn_sched_barrier(0);
    }
    if (tt < 14)
      stage16(Kp + (size_t)((tt + 2) * 64 + kt_t) * 64 + kt_d, Ks[(tt + 2) & 3] + w4 * 512, lane);
    unsigned long long mw0 = __shfl(mq[0][tt & 3], ((tt >> 2) << 4) + la);
    unsigned long long mw1 = __shfl(mq[1][tt & 3], ((tt >> 2) << 4) + la);
    unsigned long long mq0s = mw0 >> (qd * 4);
    unsigned long long mq1s = mw1 >> (qd * 4);
#pragma unroll
    for (int tsub = 0; tsub < 4; tsub++) {
      half8 kf0 = *(const half8*)(ks_ + (tsub * 16 + la) * 32 + kc8);
      half8 kf1 = *(const half8*)(ks_ + 2048 + (tsub * 16 + la) * 32 + kc8);
      f32x4 a0 = {}, a1 = {};
      __builtin_amdgcn_s_setprio(1);
      a0 = __builtin_amdgcn_mfma_f32_16x16x32_f16(kf0, qf[0][0], a0, 0, 0, 0);
      a1 = __builtin_amdgcn_mfma_f32_16x16x32_f16(kf0, qf[1][0], a1, 0, 0, 0);
      a0 = __builtin_amdgcn_mfma_f32_16x16x32_f16(kf1, qf[0][1], a0, 0, 0, 0);
      a1 = __builtin_amdgcn_mfma_f32_16x16x32_f16(kf1, qf[1][1], a1, 0, 0, 0);
      __builtin_amdgcn_s_setprio(0);
      half4 pf[2];
#pragma unroll
      for (int qi = 0; qi < 2; qi++) {
        const f32x4& aa = qi ? a1 : a0;
        unsigned nib = (unsigned)((qi ? mq1s : mq0s) >> (tsub * 16)) & 15u;
#ifdef HAVE_PKRTZ
        // unconditional exp (bounded; cvt_pkrtz clamps, never inf) then exact {0,1} pk_mul.
        float e0 = EXP2(aa[0]);
        float e1 = EXP2(aa[1]);
        float e2 = EXP2(aa[2]);
        float e3 = EXP2(aa[3]);
        fp16x4 lv = *(const fp16x4*)lut16[nib];  // ds_read_b64: broadcast/conflict-free
        fp16x2 l01 = __builtin_shufflevector(lv, lv, 0, 1);
        fp16x2 l23 = __builtin_shufflevector(lv, lv, 2, 3);
        fp16x2 p01 = __builtin_amdgcn_cvt_pkrtz(e0, e1) * l01;  // v_pk_mul_f16
        fp16x2 p23 = __builtin_amdgcn_cvt_pkrtz(e2, e3) * l23;
        fp16x4 pfv = __builtin_shufflevector(p01, p23, 0, 1, 2, 3);
        pf[qi] = __builtin_bit_cast(half4, pfv);
#if defined(HAVE_FDOT2)
        rs[qi] = __builtin_amdgcn_fdot2(p01, one2, rs[qi], false);
        rs[qi] = __builtin_amdgcn_fdot2(p23, one2, rs[qi], false);
#else
        rs[qi] += (float)p01[0] + (float)p01[1] + (float)p23[0] + (float)p23[1];
#endif
#else
        float e0 = (nib & 1u) ? EXP2(aa[0]) : 0.0f;
        float e1 = (nib & 2u) ? EXP2(aa[1]) : 0.0f;
        float e2 = (nib & 4u) ? EXP2(aa[2]) : 0.0f;
        float e3 = (nib & 8u) ? EXP2(aa[3]) : 0.0f;
        pf[qi][0] = (_Float16)e0; pf[qi][1] = (_Float16)e1;
        pf[qi][2] = (_Float16)e2; pf[qi][3] = (_Float16)e3;
        rs[qi] += e0 + e1 + e2 + e3;
#endif
      }
#pragma unroll
      for (int nsub = 0; nsub < 4; nsub++) {
        half4 vf = *(const half4*)(vs_ + (tsub >> 1) * 2560 + (nsub * 16 + la) * 40 +
                                   (tsub & 1) * 16 + qd * 4);
        __builtin_amdgcn_s_setprio(1);
        acco[0][nsub] = __builtin_amdgcn_mfma_f32_16x16x16f16(pf[0], vf, acco[0][nsub], 0, 0, 0);
        acco[1][nsub] = __builtin_amdgcn_mfma_f32_16x16x16f16(pf[1], vf, acco[1][nsub], 0, 0, 0);
        __builtin_amdgcn_s_setprio(0);
      }
    }
    if (tt < 15) *(half8*)(Vs[(tt + 1) & 1] + vs_off) = vvn;
    if (tt < 14) {
      asm volatile("s_waitcnt vmcnt(1) lgkmcnt(0)" ::: "memory");
      BARRIER();
    } else if (tt == 14) {
      asm volatile("s_waitcnt vmcnt(0) lgkmcnt(0)" ::: "memory");
      BARRIER();
    }
  }
  float* op = out + (size_t)b * 1024 * 1024 + (size_t)h * 64;
#pragma unroll
  for (int qi = 0; qi < 2; qi++) {
    float r0 = rs[qi];
    r0 += __shfl_xor(r0, 16);
    r0 += __shfl_xor(r0, 32);
    float inv_q = 1.0f / (r0 + 1e-8f);
#pragma unroll
    for (int rg = 0; rg < 4; rg++) {
      float inv = __shfl(inv_q, qd * 4 + rg);
      int s = q0w + qi * 128 + qd * 4 + rg;
#pragma unroll
      for (int nsub = 0; nsub < 4; nsub++)
        op[(size_t)s * 1024 + nsub * 16 + la] = acco[qi][nsub][rg] * inv;
    }
  }
}

extern "C" void kernel_launch(void* const* d_in, const int* in_sizes, int n_in,
                              void* d_out, int out_size, void* d_ws, size_t ws_size,
                              hipStream_t stream) {
  (void)in_sizes; (void)n_in; (void)out_size; (void)ws_size;
  const float* x = (const float*)d_in[0];
  const float* am = (const float*)d_in[1];
  const float* Wq = (const float*)d_in[2];
  const float* Wk = (const float*)d_in[3];
  const float* Wv = (const float*)d_in[4];
  float* out = (float*)d_out;

  char* p = (char*)d_ws;
  _Float16* xb = (_Float16*)p;    p += (size_t)8192 * 1024 * 2;
  _Float16* Wqkvt = (_Float16*)p; p += (size_t)3 * 1024 * 1024 * 2;
  _Float16* Qt = (_Float16*)p;    p += (size_t)8192 * 1024 * 2;   // [b,h,d,s]
  _Float16* Kh = (_Float16*)p;    p += (size_t)8192 * 1024 * 2;   // [b,h,s,d]
  _Float16* Vth = (_Float16*)p;   p += (size_t)8192 * 1024 * 2;   // [b,h,d,s]
  unsigned long long* mb = (unsigned long long*)p;

  prep_kernel<<<19456, 256, 0, stream>>>(x, am, Wq, Wk, Wv, xb, Wqkvt, mb);
  gemm_kernel<<<dim3(512), 512, 0, stream>>>(xb, Wqkvt, Qt, Kh, Vth);
  attn_kernel<<<512, 512, 0, stream>>>(Qt, Kh, Vth, mb, out);
}